// Round 22
// baseline (396.782 us; speedup 1.0000x reference)
//
#include <hip/hip_runtime.h>

#define B_    1024
#define AB_   6
#define BIN_  16
#define BOUT_ 32

typedef float f4 __attribute__((ext_vector_type(4)));
typedef _Float16 hlf4 __attribute__((ext_vector_type(4)));

#define SOFTBAR()                                                  \
    do {                                                           \
        asm volatile("s_waitcnt lgkmcnt(0)" ::: "memory");         \
        __builtin_amdgcn_s_barrier();                              \
        __builtin_amdgcn_sched_barrier(0);                         \
    } while (0)

// ---------------------------------------------------------------------------
// R22: PHASE-ABLATION DIAGNOSTIC (R21 plateau 108.5; three structural
// theories dead; phase costs unknown). Probes on the l8 geometry, REP'd
// past fillBuffer's ~255us so each gets a PMC row. MODE: 0=full body,
// 1=compute-only (MFMA + ds_write, no global stores), 2=flush-only
// (LDS-read + dense stores, no compute). Final dispatch = real R21 kernel
// (writes every output correctly; probes' garbage is overwritten).
// ---------------------------------------------------------------------------
template<int NSH, int SPB, int MODE, int REP>
__device__ __forceinline__ void probe_body(const float* __restrict__ X,
                                           const float* __restrict__ W,
                                           float* __restrict__ OUT,
                                           float* os, int bi) {
    constexpr int SZ   = BIN_ * NSH;
    constexpr int NOUT = BOUT_ * NSH * NSH;
    constexpr int NT   = (BOUT_ * NSH) / 16;
    constexpr int MT   = (NSH + 15) / 16;
    constexpr int NTQ  = (NT + 3) / 4;

    const int tid  = threadIdx.x;
    const int lane = tid & 63;
    const int w    = tid >> 6;
    const int lm   = lane & 15;
    const int lk   = (lane >> 4) * 4;

    const int ab = bi % AB_;
    const int g  = bi / AB_;

    const float* Wab = W + (size_t)ab * (BIN_ * BOUT_ * NSH);

    hlf4 bfrag[NTQ];
    if constexpr (MODE != 2) {
#pragma unroll
        for (int t = 0; t < NTQ; ++t) {
            const int ni = w * NTQ + t;
            if (ni < NT) {
                const int n = ni * 16 + lm;
#pragma unroll
                for (int j = 0; j < 4; ++j)
                    bfrag[t][j] = (_Float16)Wab[(lk + j) * (BOUT_ * NSH) + n];
            }
        }
    }

    auto load_a = [&](int slice, hlf4* dst) {
        const float* Xs = X + (size_t)slice * SZ;
#pragma unroll
        for (int mi = 0; mi < MT; ++mi) {
            const int l  = mi * 16 + lm;
            const int lc = (l > NSH - 1) ? (NSH - 1) : l;
#pragma unroll
            for (int j = 0; j < 4; ++j)
                dst[mi][j] = (_Float16)Xs[(lk + j) * NSH + lc];
        }
    };

    for (int rep = 0; rep < REP; ++rep) {
        asm volatile("" ::: "memory");
        hlf4 acur[MT], anext[MT];
        if constexpr (MODE != 2) load_a(ab + AB_ * (g * SPB), acur);

        for (int s = 0; s < SPB; ++s) {
            const int slice = ab + AB_ * (g * SPB + s);

            if constexpr (MODE != 2) {
#pragma unroll
                for (int t = 0; t < NTQ; ++t) {
                    const int ni = w * NTQ + t;
                    if (ni < NT) {
                        const int n  = ni * 16 + lm;
                        const int o  = n / NSH;
                        const int kq = n - o * NSH;
                        float* base = os + o * (NSH * NSH) + kq;
#pragma unroll
                        for (int mi = 0; mi < MT; ++mi) {
                            f4 d = __builtin_amdgcn_mfma_f32_16x16x16f16(
                                acur[mi], bfrag[t], (f4){0.f, 0.f, 0.f, 0.f}, 0, 0, 0);
#pragma unroll
                            for (int j = 0; j < 4; ++j) {
                                const int l = mi * 16 + lk + j;
                                if (l < NSH) base[l * NSH] = d[j];
                            }
                        }
                    }
                }
            }
            SOFTBAR();
            if constexpr (MODE != 2) {
                if (s + 1 < SPB) load_a(slice + AB_, anext);
            }
            if constexpr (MODE != 1) {
                f4* dst = (f4*)(OUT + (size_t)slice * NOUT);
                const f4* src = (const f4*)os;
                for (int c = tid; c < NOUT / 4; c += 256) dst[c] = src[c];
            }
            SOFTBAR();
            if constexpr (MODE != 2) {
#pragma unroll
                for (int mi = 0; mi < MT; ++mi) acur[mi] = anext[mi];
            }
        }
    }
}

__global__ __launch_bounds__(256, 4)
void probe_flush(const float* __restrict__ X, const float* __restrict__ W,
                 float* __restrict__ OUT) {
    __shared__ __attribute__((aligned(16))) float os[BOUT_ * 17 * 17];
    probe_body<17, 8, 2, 12>(X, W, OUT, os, blockIdx.x);
}

__global__ __launch_bounds__(256, 4)
void probe_comp(const float* __restrict__ X, const float* __restrict__ W,
                float* __restrict__ OUT) {
    __shared__ __attribute__((aligned(16))) float os[BOUT_ * 17 * 17];
    probe_body<17, 8, 1, 20>(X, W, OUT, os, blockIdx.x);
}

__global__ __launch_bounds__(256, 4)
void probe_full(const float* __restrict__ X, const float* __restrict__ W,
                float* __restrict__ OUT) {
    __shared__ __attribute__((aligned(16))) float os[BOUT_ * 17 * 17];
    probe_body<17, 8, 0, 8>(X, W, OUT, os, blockIdx.x);
}

// ------------------------- real kernel (R21, unchanged) -------------------
template<int NSH, int SPB>
__device__ __forceinline__ void mfma_lds_body(const float* __restrict__ X,
                                              const float* __restrict__ W,
                                              float* __restrict__ OUT,
                                              float* os, int bi) {
    probe_body<NSH, SPB, 0, 1>(X, W, OUT, os, bi);
}

__device__ __forceinline__ void l0_body(const float* __restrict__ X,
                                        const float* __restrict__ W,
                                        const float* __restrict__ bias,
                                        float* __restrict__ OUT, int b) {
    const int o  = threadIdx.x & 31;
    const int ns = threadIdx.x >> 5;
    const int n0 = (b / AB_) * 64;
    const int ab = b % AB_;
    float wv[BIN_];
#pragma unroll
    for (int i = 0; i < BIN_; ++i) wv[i] = W[(ab * BIN_ + i) * BOUT_ + o];
    const float bv = bias[ab * BOUT_ + o];
#pragma unroll
    for (int s = 0; s < 8; ++s) {
        const int n = n0 + ns + s * 8;
        const float* Xp = X + ((size_t)n * AB_ + ab) * BIN_;
        float acc = bv;
#pragma unroll
        for (int i = 0; i < BIN_; ++i) acc = fmaf(Xp[i], wv[i], acc);
        OUT[((size_t)n * AB_ + ab) * BOUT_ + o] = acc;
    }
}

#define NB8 768
#define NB6 768
#define NB4 768
#define NB2 768
#define NB0 96

__global__ __launch_bounds__(256, 4)
void s2conv_one(const float* __restrict__ x0, const float* __restrict__ x2,
                const float* __restrict__ x4, const float* __restrict__ x6,
                const float* __restrict__ x8,
                const float* __restrict__ w0, const float* __restrict__ w2,
                const float* __restrict__ w4, const float* __restrict__ w6,
                const float* __restrict__ w8,
                const float* __restrict__ bias, float* __restrict__ out,
                size_t off0, size_t off2, size_t off4, size_t off6, size_t off8) {
    __shared__ __attribute__((aligned(16))) float os[BOUT_ * 17 * 17];
    int b = blockIdx.x;
    if (b < NB8) { mfma_lds_body<17, 8>(x8, w8, out + off8, os, b); return; }
    b -= NB8;
    if (b < NB6) { mfma_lds_body<13, 8>(x6, w6, out + off6, os, b); return; }
    b -= NB6;
    if (b < NB4) { mfma_lds_body< 9, 8>(x4, w4, out + off4, os, b); return; }
    b -= NB4;
    if (b < NB2) { mfma_lds_body< 5, 8>(x2, w2, out + off2, os, b); return; }
    b -= NB2;
    l0_body(x0, w0, bias, out + off0, b);
}

extern "C" void kernel_launch(void* const* d_in, const int* in_sizes, int n_in,
                              void* d_out, int out_size, void* d_ws, size_t ws_size,
                              hipStream_t stream) {
    const float* x0 = (const float*)d_in[0];
    const float* w0 = (const float*)d_in[1];
    const float* x2 = (const float*)d_in[2];
    const float* w2 = (const float*)d_in[3];
    const float* x4 = (const float*)d_in[4];
    const float* w4 = (const float*)d_in[5];
    const float* x6 = (const float*)d_in[6];
    const float* w6 = (const float*)d_in[7];
    const float* x8 = (const float*)d_in[8];
    const float* w8 = (const float*)d_in[9];
    const float* bias = (const float*)d_in[10];
    float* out = (float*)d_out;

    const size_t per = (size_t)B_ * AB_ * BOUT_;
    size_t off0 = 0;
    size_t off2 = off0 + per * 1;
    size_t off4 = off2 + per * 25;
    size_t off6 = off4 + per * 81;
    size_t off8 = off6 + per * 169;

    // ---- diagnostics first (garbage/partial writes), real kernel last ----
    probe_flush<<<NB8, 256, 0, stream>>>(x8, w8, out + off8);
    probe_comp <<<NB8, 256, 0, stream>>>(x8, w8, out + off8);
    probe_full <<<NB8, 256, 0, stream>>>(x8, w8, out + off8);

    const int nblocks = NB8 + NB6 + NB4 + NB2 + NB0;
    s2conv_one<<<nblocks, 256, 0, stream>>>(x0, x2, x4, x6, x8,
                                            w0, w2, w4, w6, w8,
                                            bias, out,
                                            off0, off2, off4, off6, off8);
}

// Round 23
// 106.779 us; speedup vs baseline: 3.7159x; 3.7159x over previous
//
#include <hip/hip_runtime.h>

#define B_    1024
#define AB_   6
#define BIN_  16
#define BOUT_ 32

typedef float f4 __attribute__((ext_vector_type(4)));
typedef _Float16 hlf4 __attribute__((ext_vector_type(4)));

#define SOFTBAR()                                                  \
    do {                                                           \
        asm volatile("s_waitcnt lgkmcnt(0)" ::: "memory");         \
        __builtin_amdgcn_s_barrier();                              \
        __builtin_amdgcn_sched_barrier(0);                         \
    } while (0)

// out[slice, o, l, k] = sum_i X[slice, i, l] * W[ab, i, o, k]
//
// R23 = R21 with a UNIFORM 18.5 KB LDS budget -> 8 blocks/CU for ALL
// degrees. R22 diagnostic: the l8 body alone sustains 6.6 TB/s (82% peak,
// = roofline) in steady state; the fused kernel's 108us comes from the
// 37 KB static LDS (sized for l8) capping EVERY degree at 4 blocks/CU,
// starving store duty-cycle coverage for the non-l8 half of the bytes.
// Fix: l8/l6 blocks process a HALF-slice (o-range [h*16,(h+1)*16), which is
// output-contiguous), l4/l2 full slices; max LDS = 16*17*17*4 = 18.5 KB.
// Bodies otherwise byte-identical to R21 (MFMA frags, A-prefetch, SOFTBAR,
// dense f4 flush).
template<int NSH, int OH, int SPB>
__device__ __forceinline__ void mfma_lds_body(const float* __restrict__ X,
                                              const float* __restrict__ W,
                                              float* __restrict__ OUT,
                                              float* os, int b) {
    constexpr int OPB  = BOUT_ / OH;           // o's per block
    constexpr int SZ   = BIN_ * NSH;
    constexpr int NOUT = BOUT_ * NSH * NSH;
    constexpr int USZ  = OPB * NSH * NSH;      // floats staged per slice
    constexpr int NTU  = (OPB * NSH) / 16;     // N-tiles per block
    constexpr int MT   = (NSH + 15) / 16;      // M-tiles (tail rows masked)
    constexpr int NTQ  = (NTU + 3) / 4;        // N-tiles per wave

    const int tid  = threadIdx.x;
    const int lane = tid & 63;
    const int w    = tid >> 6;                 // wave 0..3
    const int lm   = lane & 15;                // A-row / B-col / D-col
    const int lk   = (lane >> 4) * 4;          // A/B k-chunk; D row-chunk

    const int h  = (OH == 2) ? (b & 1) : 0;    // o-half
    const int gi = (OH == 2) ? (b >> 1) : b;
    const int ab = gi % AB_;
    const int g  = gi / AB_;

    const float* Wab = W + (size_t)ab * (BIN_ * BOUT_ * NSH);

    // ---- hoist this wave's B-frags once per block (this block's o-range) ----
    hlf4 bfrag[NTQ];
#pragma unroll
    for (int t = 0; t < NTQ; ++t) {
        const int ni = w * NTQ + t;
        if (ni < NTU) {
            const int n = h * (OPB * NSH) + ni * 16 + lm;
#pragma unroll
            for (int j = 0; j < 4; ++j)
                bfrag[t][j] = (_Float16)Wab[(lk + j) * (BOUT_ * NSH) + n];
        }
    }

    auto load_a = [&](int slice, hlf4* dst) {  // A[row=l][k=lk+j] = X[k][l]
        const float* Xs = X + (size_t)slice * SZ;
#pragma unroll
        for (int mi = 0; mi < MT; ++mi) {
            const int l  = mi * 16 + lm;
            const int lc = (l > NSH - 1) ? (NSH - 1) : l;   // clamp, masked later
#pragma unroll
            for (int j = 0; j < 4; ++j)
                dst[mi][j] = (_Float16)Xs[(lk + j) * NSH + lc];
        }
    };

    hlf4 acur[MT], anext[MT];
    load_a(ab + AB_ * (g * SPB), acur);        // prologue

    for (int s = 0; s < SPB; ++s) {
        const int slice = ab + AB_ * (g * SPB + s);

        // ---- this wave's tiles -> LDS (local o = nl/NSH within o-range) ----
#pragma unroll
        for (int t = 0; t < NTQ; ++t) {
            const int ni = w * NTQ + t;
            if (ni < NTU) {
                const int nl = ni * 16 + lm;
                const int ol = nl / NSH;         // constexpr divisor -> magic mul
                const int kq = nl - ol * NSH;
                float* base = os + ol * (NSH * NSH) + kq;
#pragma unroll
                for (int mi = 0; mi < MT; ++mi) {
                    f4 d = __builtin_amdgcn_mfma_f32_16x16x16f16(
                        acur[mi], bfrag[t], (f4){0.f, 0.f, 0.f, 0.f}, 0, 0, 0);
#pragma unroll
                    for (int j = 0; j < 4; ++j) {
                        const int l = mi * 16 + lk + j;   // D row
                        if (l < NSH) base[l * NSH] = d[j];
                    }
                }
            }
        }
        SOFTBAR();   // ds_writes visible; global stores stay in flight

        // ---- prefetch next slice's A-frags (latency hides under flush) ----
        if (s + 1 < SPB) load_a(slice + AB_, anext);

        // ---- dense contiguous f4 flush of this block's o-range ----
        f4* dst = (f4*)(OUT + (size_t)slice * NOUT + (size_t)h * USZ);
        const f4* src = (const f4*)os;
        for (int c = tid; c < USZ / 4; c += 256) dst[c] = src[c];
        SOFTBAR();   // flush ds_reads done -> buffer reusable

#pragma unroll
        for (int mi = 0; mi < MT; ++mi) acur[mi] = anext[mi];
    }
}

// l=0: direct coalesced stores, 64 n per block.
__device__ __forceinline__ void l0_body(const float* __restrict__ X,
                                        const float* __restrict__ W,
                                        const float* __restrict__ bias,
                                        float* __restrict__ OUT, int b) {
    const int o  = threadIdx.x & 31;
    const int ns = threadIdx.x >> 5;   // 0..7
    const int n0 = (b / AB_) * 64;
    const int ab = b % AB_;
    float wv[BIN_];
#pragma unroll
    for (int i = 0; i < BIN_; ++i) wv[i] = W[(ab * BIN_ + i) * BOUT_ + o];
    const float bv = bias[ab * BOUT_ + o];
#pragma unroll
    for (int s = 0; s < 8; ++s) {
        const int n = n0 + ns + s * 8;
        const float* Xp = X + ((size_t)n * AB_ + ab) * BIN_;
        float acc = bv;
#pragma unroll
        for (int i = 0; i < BIN_; ++i) acc = fmaf(Xp[i], wv[i], acc);
        OUT[((size_t)n * AB_ + ab) * BOUT_ + o] = acc;
    }
}

#define NB8 1536   // 6144/SPB8 * 2 halves
#define NB6 1536
#define NB4 768    // full slice
#define NB2 768
#define NB0 96

__global__ __launch_bounds__(256, 4)
void s2conv_one(const float* __restrict__ x0, const float* __restrict__ x2,
                const float* __restrict__ x4, const float* __restrict__ x6,
                const float* __restrict__ x8,
                const float* __restrict__ w0, const float* __restrict__ w2,
                const float* __restrict__ w4, const float* __restrict__ w6,
                const float* __restrict__ w8,
                const float* __restrict__ bias, float* __restrict__ out,
                size_t off0, size_t off2, size_t off4, size_t off6, size_t off8) {
    __shared__ __attribute__((aligned(16))) float os[16 * 17 * 17];  // 18.5 KB
    int b = blockIdx.x;                        // big degrees first
    if (b < NB8) { mfma_lds_body<17, 2, 8>(x8, w8, out + off8, os, b); return; }
    b -= NB8;
    if (b < NB6) { mfma_lds_body<13, 2, 8>(x6, w6, out + off6, os, b); return; }
    b -= NB6;
    if (b < NB4) { mfma_lds_body< 9, 1, 8>(x4, w4, out + off4, os, b); return; }
    b -= NB4;
    if (b < NB2) { mfma_lds_body< 5, 1, 8>(x2, w2, out + off2, os, b); return; }
    b -= NB2;
    l0_body(x0, w0, bias, out + off0, b);
}

extern "C" void kernel_launch(void* const* d_in, const int* in_sizes, int n_in,
                              void* d_out, int out_size, void* d_ws, size_t ws_size,
                              hipStream_t stream) {
    const float* x0 = (const float*)d_in[0];
    const float* w0 = (const float*)d_in[1];
    const float* x2 = (const float*)d_in[2];
    const float* w2 = (const float*)d_in[3];
    const float* x4 = (const float*)d_in[4];
    const float* w4 = (const float*)d_in[5];
    const float* x6 = (const float*)d_in[6];
    const float* w6 = (const float*)d_in[7];
    const float* x8 = (const float*)d_in[8];
    const float* w8 = (const float*)d_in[9];
    const float* bias = (const float*)d_in[10];
    float* out = (float*)d_out;

    const size_t per = (size_t)B_ * AB_ * BOUT_;
    size_t off0 = 0;
    size_t off2 = off0 + per * 1;
    size_t off4 = off2 + per * 25;
    size_t off6 = off4 + per * 81;
    size_t off8 = off6 + per * 169;

    const int nblocks = NB8 + NB6 + NB4 + NB2 + NB0;   // 4704
    s2conv_one<<<nblocks, 256, 0, stream>>>(x0, x2, x4, x6, x8,
                                            w0, w2, w4, w6, w8,
                                            bias, out,
                                            off0, off2, off4, off6, off8);
}